// Round 2
// baseline (1683.000 us; speedup 1.0000x reference)
//
#include <hip/hip_runtime.h>

#define NN 50000
#define NE 640000

typedef __bf16 bf16x8 __attribute__((ext_vector_type(8)));
typedef short  short8 __attribute__((ext_vector_type(8)));
typedef float  f32x4  __attribute__((ext_vector_type(4)));

__device__ __forceinline__ short f2bf(float v) {
  unsigned u = __builtin_bit_cast(unsigned, v);
  u = (u + 0x7FFFu + ((u >> 16) & 1u)) >> 16;   // RNE
  return (short)u;
}
__device__ __forceinline__ float bf2f(short s) {
  unsigned u = ((unsigned)(unsigned short)s) << 16;
  return __builtin_bit_cast(float, u);
}
__device__ __forceinline__ float silu_f(float v) {
  return v / (1.0f + __expf(-v));
}
__device__ __forceinline__ bf16x8 ld8(const short* p) {
  return *(const bf16x8*)(p);
}

// ---------------- prep: bf16 weight transposes + str convert + degree ----------------
__global__ void egcl_prep(const float* __restrict__ mw1, const float* __restrict__ mw2,
                          const float* __restrict__ tw1, const float* __restrict__ tw2,
                          const float* __restrict__ pw1, const float* __restrict__ pw2,
                          const float* __restrict__ strf, const int* __restrict__ rowp,
                          short* __restrict__ w1t, short* __restrict__ w2t,
                          short* __restrict__ t1t, short* __restrict__ t2t,
                          short* __restrict__ p1t, short* __restrict__ p2t,
                          short* __restrict__ strb, int* __restrict__ deg)
{
  const int S1 = 65536, S2 = 98304, S3 = 32768, SS = NN * 128;
  const int total = 4 * S1 + S2 + S3 + SS + NE;
  int stride = gridDim.x * blockDim.x;
  for (int i = blockIdx.x * blockDim.x + threadIdx.x; i < total; i += stride) {
    int j = i;
    if (j < S1) { int n = j >> 8, k = j & 255; w1t[j] = f2bf(mw1[k * 256 + n]); continue; }
    j -= S1;
    if (j < S1) { int n = j >> 8, k = j & 255; w2t[j] = f2bf(mw2[k * 256 + n]); continue; }
    j -= S1;
    if (j < S1) { int n = j >> 8, k = j & 255; t1t[j] = f2bf(tw1[k * 256 + n]); continue; }
    j -= S1;
    if (j < S1) { int n = j >> 8, k = j & 255; t2t[j] = f2bf(tw2[k * 256 + n]); continue; }
    j -= S1;
    if (j < S2) { int n = j / 384, k = j - n * 384; p1t[j] = f2bf(pw1[k * 256 + n]); continue; }
    j -= S2;
    if (j < S3) { int n = j >> 8, k = j & 255; p2t[j] = f2bf(pw2[k * 128 + n]); continue; }
    j -= S3;
    if (j < SS) { strb[j] = f2bf(strf[j]); continue; }
    j -= SS;
    atomicAdd(deg + rowp[j], 1);
  }
}

// ---------------- exclusive prefix scan of deg -> base (single block, wave scans) ----
__global__ __launch_bounds__(1024)
void egcl_scan(const int* __restrict__ deg, int* __restrict__ base)
{
  __shared__ int wsum[16], wincl[16];
  __shared__ int carry_s;
  const int tid = threadIdx.x, lane = tid & 63, w = tid >> 6;
  if (tid == 0) carry_s = 0;
  __syncthreads();
  for (int start = 0; start < NN; start += 1024) {
    const int i = start + tid;
    int v = (i < NN) ? deg[i] : 0;
    int s = v;
#pragma unroll
    for (int off = 1; off < 64; off <<= 1) {
      int t = __shfl_up(s, off);
      if (lane >= off) s += t;
    }
    if (lane == 63) wsum[w] = s;
    __syncthreads();
    if (w == 0) {
      int u = (lane < 16) ? wsum[lane] : 0;
#pragma unroll
      for (int off = 1; off < 16; off <<= 1) {
        int t = __shfl_up(u, off);
        if (lane >= off) u += t;
      }
      if (lane < 16) wincl[lane] = u;
    }
    __syncthreads();
    const int waveoff = wincl[w] - wsum[w];
    const int carry = carry_s;
    if (i < NN) base[i] = carry + waveoff + s - v;
    __syncthreads();
    if (tid == 0) carry_s = carry + wincl[15];
    __syncthreads();
  }
  if (tid == 0) base[NN] = NE;
}

// ---------------- scatter edge ids into CSR buckets ----------------
__global__ void egcl_scatter(const int* __restrict__ rowp, const int* __restrict__ base,
                             int* __restrict__ cursor, int* __restrict__ eidg)
{
  int stride = gridDim.x * blockDim.x;
  for (int e = blockIdx.x * blockDim.x + threadIdx.x; e < NE; e += stride) {
    int r = rowp[e];
    int pos = base[r] + atomicAdd(cursor + r, 1);
    eidg[pos] = e;
  }
}

// ---------------- edge kernel (CSR-ordered) ----------------
// 512 thr = 8 waves; 128 CSR positions/wg; wave = (wm:2)x(wn:4); 4x4 tiles of 16x16.
// LDS Ab: [128][264] bf16, in-place between layers (read-all -> barrier -> write).

__device__ __forceinline__ void gemm_k256(const short* Ab, const short* __restrict__ WT,
                                          int wm, int wn, int l16, int quad,
                                          f32x4 acc[4][4])
{
#pragma unroll
  for (int nt = 0; nt < 4; ++nt)
#pragma unroll
    for (int mt = 0; mt < 4; ++mt)
      acc[nt][mt] = (f32x4)(0.0f);
#pragma unroll
  for (int ks = 0; ks < 8; ++ks) {
    const int kb = ks * 32 + quad * 8;
    bf16x8 b[4];
#pragma unroll
    for (int nt = 0; nt < 4; ++nt)
      b[nt] = ld8(WT + (wn * 64 + nt * 16 + l16) * 256 + kb);
#pragma unroll
    for (int mt = 0; mt < 4; ++mt) {
      bf16x8 a = ld8(Ab + (wm * 64 + mt * 16 + l16) * 264 + kb);
#pragma unroll
      for (int nt = 0; nt < 4; ++nt)
        acc[nt][mt] = __builtin_amdgcn_mfma_f32_16x16x32_bf16(a, b[nt], acc[nt][mt], 0, 0, 0);
    }
  }
}

template <bool L1>
__device__ __forceinline__ void epi_write(short* Ab, f32x4 acc[4][4],
                                          const float* __restrict__ bias,
                                          const float* __restrict__ w1last,
                                          const float* dist_s,
                                          int wm, int wn, int l16, int quad)
{
#pragma unroll
  for (int nt = 0; nt < 4; ++nt) {
    const int n = wn * 64 + nt * 16 + l16;
    const float bn = bias[n];
    float wd = 0.0f;
    if constexpr (L1) wd = w1last[n];
#pragma unroll
    for (int mt = 0; mt < 4; ++mt) {
#pragma unroll
      for (int r = 0; r < 4; ++r) {
        const int m = wm * 64 + mt * 16 + quad * 4 + r;
        float v = acc[nt][mt][r] + bn;
        if constexpr (L1) v += dist_s[m] * wd;
        Ab[m * 264 + n] = f2bf(silu_f(v));
      }
    }
  }
}

__global__ __launch_bounds__(512, 4)
void egcl_edge(const int* __restrict__ eidx, const float* __restrict__ coord,
               const short* __restrict__ strb, const int* __restrict__ eidg,
               const short* __restrict__ w1t, const short* __restrict__ w2t,
               const short* __restrict__ t1t, const short* __restrict__ t2t,
               const float* __restrict__ msg_w1, const float* __restrict__ msg_b1,
               const float* __restrict__ msg_b2, const float* __restrict__ tr_b1,
               const float* __restrict__ tr_b2, const float* __restrict__ tr_w3,
               float* __restrict__ msg_sum, float* __restrict__ trans_sum)
{
  __shared__ short Ab[128 * 264];
  __shared__ int   rs_s[128], cs_s[128];
  __shared__ float dist_s[128], cdx_s[128], cdy_s[128], cdz_s[128], gate_s[128];

  const int tid  = threadIdx.x;
  const int lane = tid & 63, wave = tid >> 6;
  const int quad = lane >> 4, l16 = lane & 15;
  const int wm = wave >> 2, wn = wave & 3;
  const int p0 = blockIdx.x * 128;
  const int* __restrict__ rowp = eidx;
  const int* __restrict__ colp = eidx + NE;

  if (tid < 128) {
    int e = eidg[p0 + tid];
    int r = rowp[e], c = colp[e];
    rs_s[tid] = r; cs_s[tid] = c;
    float dx = coord[r * 3 + 0] - coord[c * 3 + 0];
    float dy = coord[r * 3 + 1] - coord[c * 3 + 1];
    float dz = coord[r * 3 + 2] - coord[c * 3 + 2];
    cdx_s[tid] = dx; cdy_s[tid] = dy; cdz_s[tid] = dz;
    dist_s[tid] = dx * dx + dy * dy + dz * dz;
  }
  __syncthreads();
  // stage A = [str[row] | str[col]] as bf16, 16B chunks
#pragma unroll
  for (int it = 0; it < 8; ++it) {
    int i = tid + it * 512;
    int e = i >> 5, cc = i & 31;
    int node = (cc < 16) ? rs_s[e] : cs_s[e];
    short8 v = *(const short8*)(strb + node * 128 + (cc & 15) * 8);
    *(short8*)(Ab + e * 264 + cc * 8) = v;
  }
  __syncthreads();

  f32x4 acc[4][4];

  // L1: edge_in @ msg_w1 (+dist col) -> silu
  gemm_k256(Ab, w1t, wm, wn, l16, quad, acc);
  __syncthreads();
  epi_write<true>(Ab, acc, msg_b1, msg_w1 + 256 * 256, dist_s, wm, wn, l16, quad);
  __syncthreads();

  // L2: -> msg
  gemm_k256(Ab, w2t, wm, wn, l16, quad, acc);
  __syncthreads();
  epi_write<false>(Ab, acc, msg_b2, nullptr, dist_s, wm, wn, l16, quad);
  __syncthreads();

  // L3 gemm reads msg; segment-reduce msg by row (CSR-sorted) before overwrite
  gemm_k256(Ab, t1t, wm, wn, l16, quad, acc);
  {
    const int c = tid & 255;
    const int ebase = (tid >> 8) * 64;
    float run = 0.0f;
    int prev = rs_s[ebase];
#pragma unroll 4
    for (int i = 0; i < 64; ++i) {
      const int r = rs_s[ebase + i];
      const float v = bf2f(Ab[(ebase + i) * 264 + c]);
      if (r != prev) { atomicAdd(msg_sum + prev * 256 + c, run); run = 0.0f; prev = r; }
      run += v;
    }
    atomicAdd(msg_sum + prev * 256 + c, run);
  }
  __syncthreads();
  epi_write<false>(Ab, acc, tr_b1, nullptr, dist_s, wm, wn, l16, quad);
  __syncthreads();

  // L4
  gemm_k256(Ab, t2t, wm, wn, l16, quad, acc);
  __syncthreads();
  epi_write<false>(Ab, acc, tr_b2, nullptr, dist_s, wm, wn, l16, quad);
  __syncthreads();

  // gate = T2 @ tr_w3
  {
    const int e = tid >> 2, p = tid & 3;
    const short* ap = Ab + e * 264 + p * 64;
    const float* wp = tr_w3 + p * 64;
    float s = 0.0f;
#pragma unroll
    for (int k = 0; k < 64; ++k) s += bf2f(ap[k]) * wp[k];
    s += __shfl_xor(s, 1);
    s += __shfl_xor(s, 2);
    if (p == 0) gate_s[e] = s;
  }
  __syncthreads();
  // trans segment-reduce by row (3 threads, one per coord component)
  if (tid < 3) {
    const int c = tid;
    float run = 0.0f;
    int prev = rs_s[0];
    for (int i = 0; i < 128; ++i) {
      const int r = rs_s[i];
      if (r != prev) { atomicAdd(trans_sum + prev * 3 + c, run); run = 0.0f; prev = r; }
      const float cd = (c == 0) ? cdx_s[i] : ((c == 1) ? cdy_s[i] : cdz_s[i]);
      run += cd * gate_s[i];
    }
    atomicAdd(trans_sum + prev * 3 + c, run);
  }
}

// ---------------- node kernel ----------------
// 256 thr = 4 waves; 64 nodes/wg; K1=384 -> N=256 (silu), K2=256 -> N=128 (+residual)
__global__ __launch_bounds__(256, 3)
void egcl_node(const float* __restrict__ strf, const float* __restrict__ coord,
               const short* __restrict__ strb,
               const short* __restrict__ p1t, const short* __restrict__ p2t,
               const float* __restrict__ pb1, const float* __restrict__ pb2,
               const float* __restrict__ msg_sum, const float* __restrict__ trans_sum,
               const int* __restrict__ deg, float* __restrict__ out)
{
  __shared__ short Ab[64 * 392];
  const int tid  = threadIdx.x;
  const int lane = tid & 63, wave = tid >> 6;
  const int quad = lane >> 4, l16 = lane & 15;
  const int n0 = blockIdx.x * 64;

#pragma unroll
  for (int it = 0; it < 4; ++it) {          // str cols 0..127
    int i = tid + it * 256;
    int m = i >> 4, c = i & 15;
    int n = n0 + m;
    short8 v = (short8)(short)0;
    if (n < NN) v = *(const short8*)(strb + n * 128 + c * 8);
    *(short8*)(Ab + m * 392 + c * 8) = v;
  }
#pragma unroll
  for (int it = 0; it < 8; ++it) {          // msg_sum cols 128..383
    int i = tid + it * 256;
    int m = i >> 5, c = i & 31;
    int n = n0 + m;
    short8 v = (short8)(short)0;
    if (n < NN) {
      const float* src = msg_sum + n * 256 + c * 8;
#pragma unroll
      for (int j = 0; j < 8; ++j) v[j] = f2bf(src[j]);
    }
    *(short8*)(Ab + m * 392 + 128 + c * 8) = v;
  }
  __syncthreads();

  f32x4 acc[4][4];
#pragma unroll
  for (int nt = 0; nt < 4; ++nt)
#pragma unroll
    for (int mt = 0; mt < 4; ++mt) acc[nt][mt] = (f32x4)(0.0f);
#pragma unroll
  for (int ks = 0; ks < 12; ++ks) {
    const int kb = ks * 32 + quad * 8;
    bf16x8 b[4];
#pragma unroll
    for (int nt = 0; nt < 4; ++nt)
      b[nt] = ld8(p1t + (wave * 64 + nt * 16 + l16) * 384 + kb);
#pragma unroll
    for (int mt = 0; mt < 4; ++mt) {
      bf16x8 a = ld8(Ab + (mt * 16 + l16) * 392 + kb);
#pragma unroll
      for (int nt = 0; nt < 4; ++nt)
        acc[nt][mt] = __builtin_amdgcn_mfma_f32_16x16x32_bf16(a, b[nt], acc[nt][mt], 0, 0, 0);
    }
  }
  __syncthreads();
#pragma unroll
  for (int nt = 0; nt < 4; ++nt) {
    const int n = wave * 64 + nt * 16 + l16;
    const float bn = pb1[n];
#pragma unroll
    for (int mt = 0; mt < 4; ++mt)
#pragma unroll
      for (int r = 0; r < 4; ++r) {
        const int m = mt * 16 + quad * 4 + r;
        Ab[m * 392 + n] = f2bf(silu_f(acc[nt][mt][r] + bn));
      }
  }
  __syncthreads();

  f32x4 a2[2][4];
#pragma unroll
  for (int nt = 0; nt < 2; ++nt)
#pragma unroll
    for (int mt = 0; mt < 4; ++mt) a2[nt][mt] = (f32x4)(0.0f);
#pragma unroll
  for (int ks = 0; ks < 8; ++ks) {
    const int kb = ks * 32 + quad * 8;
    bf16x8 b0 = ld8(p2t + (wave * 32 + l16) * 256 + kb);
    bf16x8 b1 = ld8(p2t + (wave * 32 + 16 + l16) * 256 + kb);
#pragma unroll
    for (int mt = 0; mt < 4; ++mt) {
      bf16x8 a = ld8(Ab + (mt * 16 + l16) * 392 + kb);
      a2[0][mt] = __builtin_amdgcn_mfma_f32_16x16x32_bf16(a, b0, a2[0][mt], 0, 0, 0);
      a2[1][mt] = __builtin_amdgcn_mfma_f32_16x16x32_bf16(a, b1, a2[1][mt], 0, 0, 0);
    }
  }
#pragma unroll
  for (int nt = 0; nt < 2; ++nt) {
    const int c = wave * 32 + nt * 16 + l16;
    const float bc = pb2[c];
#pragma unroll
    for (int mt = 0; mt < 4; ++mt)
#pragma unroll
      for (int r = 0; r < 4; ++r) {
        const int m = mt * 16 + quad * 4 + r;
        const int n = n0 + m;
        if (n < NN) out[n * 128 + c] = strf[n * 128 + c] + a2[nt][mt][r] + bc;
      }
  }
  if (tid < 64) {
    const int n = n0 + tid;
    if (n < NN) {
      float cv = (float)deg[n]; if (cv < 1.0f) cv = 1.0f;
      float inv = 1.0f / cv;
      out[NN * 128 + n * 3 + 0] = coord[n * 3 + 0] + trans_sum[n * 3 + 0] * inv;
      out[NN * 128 + n * 3 + 1] = coord[n * 3 + 1] + trans_sum[n * 3 + 1] * inv;
      out[NN * 128 + n * 3 + 2] = coord[n * 3 + 2] + trans_sum[n * 3 + 2] * inv;
    }
  }
}

extern "C" void kernel_launch(void* const* d_in, const int* in_sizes, int n_in,
                              void* d_out, int out_size, void* d_ws, size_t ws_size,
                              hipStream_t stream)
{
  const int*   eidx   = (const int*)d_in[0];
  const float* strf   = (const float*)d_in[1];
  const float* coord  = (const float*)d_in[2];
  const float* msg_w1 = (const float*)d_in[3];
  const float* msg_b1 = (const float*)d_in[4];
  const float* msg_w2 = (const float*)d_in[5];
  const float* msg_b2 = (const float*)d_in[6];
  const float* tr_w1  = (const float*)d_in[7];
  const float* tr_b1  = (const float*)d_in[8];
  const float* tr_w2  = (const float*)d_in[9];
  const float* tr_b2  = (const float*)d_in[10];
  const float* tr_w3  = (const float*)d_in[11];
  const float* posi_w1 = (const float*)d_in[12];
  const float* posi_b1 = (const float*)d_in[13];
  const float* posi_w2 = (const float*)d_in[14];
  const float* posi_b2 = (const float*)d_in[15];
  float* out = (float*)d_out;

  char* ws = (char*)d_ws;
  float* msg_sum   = (float*)ws;                    // [N,256] f32     (zeroed)
  float* trans_sum = msg_sum + NN * 256;            // [N,3]           (zeroed)
  int*   deg       = (int*)(trans_sum + NN * 3);    // [N]             (zeroed)
  int*   cursor    = deg + NN;                      // [N]             (zeroed)
  int*   base      = cursor + NN;                   // [N+8] (pad for 16B align)
  int*   eidg      = base + NN + 8;                 // [E]
  short* strb = (short*)(eidg + NE);                // [N,128] bf16 (16B-aligned)
  short* w1t  = strb + NN * 128;                    // [256][256]
  short* w2t  = w1t + 65536;
  short* t1t  = w2t + 65536;
  short* t2t  = t1t + 65536;
  short* p1t  = t2t + 65536;                        // [256][384]
  short* p2t  = p1t + 98304;                        // [128][256]

  const int* rowp = eidx;

  hipMemsetAsync(ws, 0, (size_t)(NN * 256 + NN * 3 + NN + NN) * 4, stream);
  egcl_prep<<<2048, 256, 0, stream>>>(msg_w1, msg_w2, tr_w1, tr_w2, posi_w1, posi_w2,
                                      strf, rowp, w1t, w2t, t1t, t2t, p1t, p2t, strb, deg);
  egcl_scan<<<1, 1024, 0, stream>>>(deg, base);
  egcl_scatter<<<2560, 256, 0, stream>>>(rowp, base, cursor, eidg);
  egcl_edge<<<NE / 128, 512, 0, stream>>>(eidx, coord, strb, eidg, w1t, w2t, t1t, t2t,
                                          msg_w1, msg_b1, msg_b2, tr_b1, tr_b2, tr_w3,
                                          msg_sum, trans_sum);
  egcl_node<<<(NN + 63) / 64, 256, 0, stream>>>(strf, coord, strb, p1t, p2t,
                                                posi_b1, posi_b2,
                                                msg_sum, trans_sum, deg, out);
}

// Round 3
// 1282.480 us; speedup vs baseline: 1.3123x; 1.3123x over previous
//
#include <hip/hip_runtime.h>

#define NN 50000
#define NE 640000

typedef __bf16 bf16x8 __attribute__((ext_vector_type(8)));
typedef short  short8 __attribute__((ext_vector_type(8)));
typedef float  f32x4  __attribute__((ext_vector_type(4)));

__device__ __forceinline__ short f2bf(float v) {
  unsigned u = __builtin_bit_cast(unsigned, v);
  u = (u + 0x7FFFu + ((u >> 16) & 1u)) >> 16;   // RNE
  return (short)u;
}
__device__ __forceinline__ float bf2f(short s) {
  unsigned u = ((unsigned)(unsigned short)s) << 16;
  return __builtin_bit_cast(float, u);
}
__device__ __forceinline__ unsigned pack2(float a, float b) {
  return (unsigned)(unsigned short)f2bf(a) | ((unsigned)(unsigned short)f2bf(b) << 16);
}
__device__ __forceinline__ float silu_f(float v) {
  return v / (1.0f + __expf(-v));
}
__device__ __forceinline__ bf16x8 ld8(const short* p) {
  return *(const bf16x8*)(p);
}
__device__ __forceinline__ void atomic_add_f(float* p, float v) {
  __hip_atomic_fetch_add(p, v, __ATOMIC_RELAXED, __HIP_MEMORY_SCOPE_AGENT);
}

// ---------------- prep: bf16 weight transposes + str convert + degree ----------------
__global__ void egcl_prep(const float* __restrict__ mw1, const float* __restrict__ mw2,
                          const float* __restrict__ tw1, const float* __restrict__ tw2,
                          const float* __restrict__ pw1, const float* __restrict__ pw2,
                          const float* __restrict__ strf, const int* __restrict__ rowp,
                          short* __restrict__ w1t, short* __restrict__ w2t,
                          short* __restrict__ t1t, short* __restrict__ t2t,
                          short* __restrict__ p1t, short* __restrict__ p2t,
                          short* __restrict__ strb, int* __restrict__ deg)
{
  const int S1 = 65536, S2 = 98304, S3 = 32768, SS = NN * 128;
  const int total = 4 * S1 + S2 + S3 + SS + NE;
  int stride = gridDim.x * blockDim.x;
  for (int i = blockIdx.x * blockDim.x + threadIdx.x; i < total; i += stride) {
    int j = i;
    if (j < S1) { int n = j >> 8, k = j & 255; w1t[j] = f2bf(mw1[k * 256 + n]); continue; }
    j -= S1;
    if (j < S1) { int n = j >> 8, k = j & 255; w2t[j] = f2bf(mw2[k * 256 + n]); continue; }
    j -= S1;
    if (j < S1) { int n = j >> 8, k = j & 255; t1t[j] = f2bf(tw1[k * 256 + n]); continue; }
    j -= S1;
    if (j < S1) { int n = j >> 8, k = j & 255; t2t[j] = f2bf(tw2[k * 256 + n]); continue; }
    j -= S1;
    if (j < S2) { int n = j / 384, k = j - n * 384; p1t[j] = f2bf(pw1[k * 256 + n]); continue; }
    j -= S2;
    if (j < S3) { int n = j >> 8, k = j & 255; p2t[j] = f2bf(pw2[k * 128 + n]); continue; }
    j -= S3;
    if (j < SS) { strb[j] = f2bf(strf[j]); continue; }
    j -= SS;
    atomicAdd(deg + rowp[j], 1);
  }
}

// ---------------- exclusive prefix scan of deg -> base (single block) ----------------
__global__ __launch_bounds__(1024)
void egcl_scan(const int* __restrict__ deg, int* __restrict__ base)
{
  __shared__ int wsum[16], wincl[16];
  __shared__ int carry_s;
  const int tid = threadIdx.x, lane = tid & 63, w = tid >> 6;
  if (tid == 0) carry_s = 0;
  __syncthreads();
  for (int start = 0; start < NN; start += 1024) {
    const int i = start + tid;
    int v = (i < NN) ? deg[i] : 0;
    int s = v;
#pragma unroll
    for (int off = 1; off < 64; off <<= 1) {
      int t = __shfl_up(s, off);
      if (lane >= off) s += t;
    }
    if (lane == 63) wsum[w] = s;
    __syncthreads();
    if (w == 0) {
      int u = (lane < 16) ? wsum[lane] : 0;
#pragma unroll
      for (int off = 1; off < 16; off <<= 1) {
        int t = __shfl_up(u, off);
        if (lane >= off) u += t;
      }
      if (lane < 16) wincl[lane] = u;
    }
    __syncthreads();
    const int waveoff = wincl[w] - wsum[w];
    const int carry = carry_s;
    if (i < NN) base[i] = carry + waveoff + s - v;
    __syncthreads();
    if (tid == 0) carry_s = carry + wincl[15];
    __syncthreads();
  }
  if (tid == 0) base[NN] = NE;
}

// ---------------- scatter edge ids into CSR buckets ----------------
__global__ void egcl_scatter(const int* __restrict__ rowp, const int* __restrict__ base,
                             int* __restrict__ cursor, int* __restrict__ eidg)
{
  int stride = gridDim.x * blockDim.x;
  for (int e = blockIdx.x * blockDim.x + threadIdx.x; e < NE; e += stride) {
    int r = rowp[e];
    int pos = base[r] + atomicAdd(cursor + r, 1);
    eidg[pos] = e;
  }
}

// ---------------- edge kernel (CSR-ordered, half-N passes, deferred writes) --------
// 512 thr = 8 waves; 128 CSR positions/wg; wave=(wm:2)x(wn:4); per half: 2x4 tiles.

__device__ __forceinline__ void gemm_half(const short* Ab, const short* __restrict__ WT,
                                          int wm, int wn, int h, int l16, int quad,
                                          f32x4 acc[2][4])
{
#pragma unroll
  for (int nt = 0; nt < 2; ++nt)
#pragma unroll
    for (int mt = 0; mt < 4; ++mt) acc[nt][mt] = (f32x4)(0.0f);
#pragma unroll
  for (int ks = 0; ks < 8; ++ks) {
    const int kb = ks * 32 + quad * 8;
    bf16x8 b0 = ld8(WT + (wn * 64 + h * 32 + l16) * 256 + kb);
    bf16x8 b1 = ld8(WT + (wn * 64 + h * 32 + 16 + l16) * 256 + kb);
#pragma unroll
    for (int mt = 0; mt < 4; ++mt) {
      bf16x8 a = ld8(Ab + (wm * 64 + mt * 16 + l16) * 264 + kb);
      acc[0][mt] = __builtin_amdgcn_mfma_f32_16x16x32_bf16(a, b0, acc[0][mt], 0, 0, 0);
      acc[1][mt] = __builtin_amdgcn_mfma_f32_16x16x32_bf16(a, b1, acc[1][mt], 0, 0, 0);
    }
  }
}

template <bool L1>
__device__ __forceinline__ void comp_pack(const f32x4 acc[2][4],
                                          const float* __restrict__ bias,
                                          const float* __restrict__ w1last,
                                          const float* dist_s,
                                          int wm, int wn, int h, int l16, int quad,
                                          uint2 pk[2][4])
{
#pragma unroll
  for (int nt = 0; nt < 2; ++nt) {
    const int n = wn * 64 + h * 32 + nt * 16 + l16;
    const float bn = bias[n];
    float wd = 0.0f;
    if constexpr (L1) wd = w1last[n];
#pragma unroll
    for (int mt = 0; mt < 4; ++mt) {
      float s[4];
#pragma unroll
      for (int r = 0; r < 4; ++r) {
        const int m = wm * 64 + mt * 16 + quad * 4 + r;
        float v = acc[nt][mt][r] + bn;
        if constexpr (L1) v += dist_s[m] * wd;
        s[r] = silu_f(v);
      }
      pk[nt][mt].x = pack2(s[0], s[1]);
      pk[nt][mt].y = pack2(s[2], s[3]);
    }
  }
}

__device__ __forceinline__ void write_pk(short* Ab, const uint2 pk0[2][4], const uint2 pk1[2][4],
                                         int wm, int wn, int l16, int quad)
{
#pragma unroll
  for (int h = 0; h < 2; ++h) {
    const uint2 (*pk)[4] = h ? pk1 : pk0;
#pragma unroll
    for (int nt = 0; nt < 2; ++nt) {
      const int n = wn * 64 + h * 32 + nt * 16 + l16;
#pragma unroll
      for (int mt = 0; mt < 4; ++mt) {
        const int m0 = wm * 64 + mt * 16 + quad * 4;
        const unsigned x = pk[nt][mt].x, y = pk[nt][mt].y;
        Ab[(m0 + 0) * 264 + n] = (short)(x & 0xFFFFu);
        Ab[(m0 + 1) * 264 + n] = (short)(x >> 16);
        Ab[(m0 + 2) * 264 + n] = (short)(y & 0xFFFFu);
        Ab[(m0 + 3) * 264 + n] = (short)(y >> 16);
      }
    }
  }
}

__global__ __launch_bounds__(512, 4)
void egcl_edge(const int* __restrict__ eidx, const float* __restrict__ coord,
               const short* __restrict__ strb, const int* __restrict__ eidg,
               const int* __restrict__ base,
               const short* __restrict__ w1t, const short* __restrict__ w2t,
               const short* __restrict__ t1t, const short* __restrict__ t2t,
               const float* __restrict__ msg_w1, const float* __restrict__ msg_b1,
               const float* __restrict__ msg_b2, const float* __restrict__ tr_b1,
               const float* __restrict__ tr_b2, const float* __restrict__ tr_w3,
               float* __restrict__ msg_sum, float* __restrict__ trans_sum)
{
  __shared__ short Ab[128 * 264];
  __shared__ int   rs_s[128], cs_s[128], own_s[128];
  __shared__ float dist_s[128], cdx_s[128], cdy_s[128], cdz_s[128], gate_s[128];

  const int tid  = threadIdx.x;
  const int lane = tid & 63, wave = tid >> 6;
  const int quad = lane >> 4, l16 = lane & 15;
  const int wm = wave >> 2, wn = wave & 3;
  const int p0 = blockIdx.x * 128;
  const int* __restrict__ rowp = eidx;
  const int* __restrict__ colp = eidx + NE;

  if (tid < 128) {
    int e = eidg[p0 + tid];
    int r = rowp[e], c = colp[e];
    rs_s[tid] = r; cs_s[tid] = c;
    // row fully contained in this thread-segment's 64-edge window?
    const int seg = p0 + (tid & ~63);
    own_s[tid] = (base[r] >= seg) && (base[r + 1] <= seg + 64) ? 1 : 0;
    float dx = coord[r * 3 + 0] - coord[c * 3 + 0];
    float dy = coord[r * 3 + 1] - coord[c * 3 + 1];
    float dz = coord[r * 3 + 2] - coord[c * 3 + 2];
    cdx_s[tid] = dx; cdy_s[tid] = dy; cdz_s[tid] = dz;
    dist_s[tid] = dx * dx + dy * dy + dz * dz;
  }
  __syncthreads();
  // stage A = [str[row] | str[col]] as bf16, 16B chunks
#pragma unroll
  for (int it = 0; it < 8; ++it) {
    int i = tid + it * 512;
    int e = i >> 5, cc = i & 31;
    int node = (cc < 16) ? rs_s[e] : cs_s[e];
    short8 v = *(const short8*)(strb + node * 128 + (cc & 15) * 8);
    *(short8*)(Ab + e * 264 + cc * 8) = v;
  }
  __syncthreads();

  f32x4 acc[2][4];
  uint2 pk0[2][4], pk1[2][4];

  // ---- L1 ----
  gemm_half(Ab, w1t, wm, wn, 0, l16, quad, acc);
  comp_pack<true>(acc, msg_b1, msg_w1 + 256 * 256, dist_s, wm, wn, 0, l16, quad, pk0);
  gemm_half(Ab, w1t, wm, wn, 1, l16, quad, acc);
  comp_pack<true>(acc, msg_b1, msg_w1 + 256 * 256, dist_s, wm, wn, 1, l16, quad, pk1);
  __syncthreads();
  write_pk(Ab, pk0, pk1, wm, wn, l16, quad);
  __syncthreads();

  // ---- L2 -> msg ----
  gemm_half(Ab, w2t, wm, wn, 0, l16, quad, acc);
  comp_pack<false>(acc, msg_b2, nullptr, dist_s, wm, wn, 0, l16, quad, pk0);
  gemm_half(Ab, w2t, wm, wn, 1, l16, quad, acc);
  comp_pack<false>(acc, msg_b2, nullptr, dist_s, wm, wn, 1, l16, quad, pk1);
  __syncthreads();
  write_pk(Ab, pk0, pk1, wm, wn, l16, quad);
  __syncthreads();

  // ---- L3 gemm (reads msg) + msg scatter (also reads msg) ----
  gemm_half(Ab, t1t, wm, wn, 0, l16, quad, acc);
  comp_pack<false>(acc, tr_b1, nullptr, dist_s, wm, wn, 0, l16, quad, pk0);
  gemm_half(Ab, t1t, wm, wn, 1, l16, quad, acc);
  comp_pack<false>(acc, tr_b1, nullptr, dist_s, wm, wn, 1, l16, quad, pk1);
  {
    const int c = tid & 255;
    const int ebase = (tid >> 8) * 64;
    float run = 0.0f;
    int prev = rs_s[ebase];
    int own  = own_s[ebase];
#pragma unroll 4
    for (int i = 0; i < 64; ++i) {
      const int idx = ebase + i;
      const int r = rs_s[idx];
      if (r != prev) {
        if (own) __builtin_nontemporal_store(run, msg_sum + prev * 256 + c);
        else     atomic_add_f(msg_sum + prev * 256 + c, run);
        run = 0.0f; prev = r; own = own_s[idx];
      }
      run += bf2f(Ab[idx * 264 + c]);
    }
    if (own) __builtin_nontemporal_store(run, msg_sum + prev * 256 + c);
    else     atomic_add_f(msg_sum + prev * 256 + c, run);
  }
  __syncthreads();
  write_pk(Ab, pk0, pk1, wm, wn, l16, quad);
  __syncthreads();

  // ---- L4 ----
  gemm_half(Ab, t2t, wm, wn, 0, l16, quad, acc);
  comp_pack<false>(acc, tr_b2, nullptr, dist_s, wm, wn, 0, l16, quad, pk0);
  gemm_half(Ab, t2t, wm, wn, 1, l16, quad, acc);
  comp_pack<false>(acc, tr_b2, nullptr, dist_s, wm, wn, 1, l16, quad, pk1);
  __syncthreads();
  write_pk(Ab, pk0, pk1, wm, wn, l16, quad);
  __syncthreads();

  // ---- gate = T2 @ tr_w3 ----
  {
    const int e = tid >> 2, p = tid & 3;
    const short* ap = Ab + e * 264 + p * 64;
    const float* wp = tr_w3 + p * 64;
    float s = 0.0f;
#pragma unroll
    for (int k = 0; k < 64; ++k) s += bf2f(ap[k]) * wp[k];
    s += __shfl_xor(s, 1);
    s += __shfl_xor(s, 2);
    if (p == 0) gate_s[e] = s;
  }
  __syncthreads();
  // trans segment-reduce by row (3 threads, one per coord component)
  if (tid < 3) {
    const int c = tid;
    float run = 0.0f;
    int prev = rs_s[0];
    for (int i = 0; i < 128; ++i) {
      const int r = rs_s[i];
      if (r != prev) { atomic_add_f(trans_sum + prev * 3 + c, run); run = 0.0f; prev = r; }
      const float cd = (c == 0) ? cdx_s[i] : ((c == 1) ? cdy_s[i] : cdz_s[i]);
      run += cd * gate_s[i];
    }
    atomic_add_f(trans_sum + prev * 3 + c, run);
  }
}

// ---------------- node kernel ----------------
__global__ __launch_bounds__(256, 3)
void egcl_node(const float* __restrict__ strf, const float* __restrict__ coord,
               const short* __restrict__ strb,
               const short* __restrict__ p1t, const short* __restrict__ p2t,
               const float* __restrict__ pb1, const float* __restrict__ pb2,
               const float* __restrict__ msg_sum, const float* __restrict__ trans_sum,
               const int* __restrict__ base, float* __restrict__ out)
{
  __shared__ short Ab[64 * 392];
  const int tid  = threadIdx.x;
  const int lane = tid & 63, wave = tid >> 6;
  const int quad = lane >> 4, l16 = lane & 15;
  const int n0 = blockIdx.x * 64;

#pragma unroll
  for (int it = 0; it < 4; ++it) {          // str cols 0..127
    int i = tid + it * 256;
    int m = i >> 4, c = i & 15;
    int n = n0 + m;
    short8 v = (short8)(short)0;
    if (n < NN) v = *(const short8*)(strb + n * 128 + c * 8);
    *(short8*)(Ab + m * 392 + c * 8) = v;
  }
#pragma unroll
  for (int it = 0; it < 8; ++it) {          // msg_sum cols 128..383
    int i = tid + it * 256;
    int m = i >> 5, c = i & 31;
    int n = n0 + m;
    short8 v = (short8)(short)0;
    if (n < NN) {
      const float* src = msg_sum + n * 256 + c * 8;
#pragma unroll
      for (int j = 0; j < 8; ++j) v[j] = f2bf(src[j]);
    }
    *(short8*)(Ab + m * 392 + 128 + c * 8) = v;
  }
  __syncthreads();

  f32x4 acc[4][4];
#pragma unroll
  for (int nt = 0; nt < 4; ++nt)
#pragma unroll
    for (int mt = 0; mt < 4; ++mt) acc[nt][mt] = (f32x4)(0.0f);
#pragma unroll
  for (int ks = 0; ks < 12; ++ks) {
    const int kb = ks * 32 + quad * 8;
    bf16x8 b[4];
#pragma unroll
    for (int nt = 0; nt < 4; ++nt)
      b[nt] = ld8(p1t + (wave * 64 + nt * 16 + l16) * 384 + kb);
#pragma unroll
    for (int mt = 0; mt < 4; ++mt) {
      bf16x8 a = ld8(Ab + (mt * 16 + l16) * 392 + kb);
#pragma unroll
      for (int nt = 0; nt < 4; ++nt)
        acc[nt][mt] = __builtin_amdgcn_mfma_f32_16x16x32_bf16(a, b[nt], acc[nt][mt], 0, 0, 0);
    }
  }
  __syncthreads();
#pragma unroll
  for (int nt = 0; nt < 4; ++nt) {
    const int n = wave * 64 + nt * 16 + l16;
    const float bn = pb1[n];
#pragma unroll
    for (int mt = 0; mt < 4; ++mt)
#pragma unroll
      for (int r = 0; r < 4; ++r) {
        const int m = mt * 16 + quad * 4 + r;
        Ab[m * 392 + n] = f2bf(silu_f(acc[nt][mt][r] + bn));
      }
  }
  __syncthreads();

  f32x4 a2[2][4];
#pragma unroll
  for (int nt = 0; nt < 2; ++nt)
#pragma unroll
    for (int mt = 0; mt < 4; ++mt) a2[nt][mt] = (f32x4)(0.0f);
#pragma unroll
  for (int ks = 0; ks < 8; ++ks) {
    const int kb = ks * 32 + quad * 8;
    bf16x8 b0 = ld8(p2t + (wave * 32 + l16) * 256 + kb);
    bf16x8 b1 = ld8(p2t + (wave * 32 + 16 + l16) * 256 + kb);
#pragma unroll
    for (int mt = 0; mt < 4; ++mt) {
      bf16x8 a = ld8(Ab + (mt * 16 + l16) * 392 + kb);
      a2[0][mt] = __builtin_amdgcn_mfma_f32_16x16x32_bf16(a, b0, a2[0][mt], 0, 0, 0);
      a2[1][mt] = __builtin_amdgcn_mfma_f32_16x16x32_bf16(a, b1, a2[1][mt], 0, 0, 0);
    }
  }
#pragma unroll
  for (int nt = 0; nt < 2; ++nt) {
    const int c = wave * 32 + nt * 16 + l16;
    const float bc = pb2[c];
#pragma unroll
    for (int mt = 0; mt < 4; ++mt)
#pragma unroll
      for (int r = 0; r < 4; ++r) {
        const int m = mt * 16 + quad * 4 + r;
        const int n = n0 + m;
        if (n < NN) out[n * 128 + c] = strf[n * 128 + c] + a2[nt][mt][r] + bc;
      }
  }
  if (tid < 64) {
    const int n = n0 + tid;
    if (n < NN) {
      float cv = (float)(base[n + 1] - base[n]); if (cv < 1.0f) cv = 1.0f;
      float inv = 1.0f / cv;
      out[NN * 128 + n * 3 + 0] = coord[n * 3 + 0] + trans_sum[n * 3 + 0] * inv;
      out[NN * 128 + n * 3 + 1] = coord[n * 3 + 1] + trans_sum[n * 3 + 1] * inv;
      out[NN * 128 + n * 3 + 2] = coord[n * 3 + 2] + trans_sum[n * 3 + 2] * inv;
    }
  }
}

extern "C" void kernel_launch(void* const* d_in, const int* in_sizes, int n_in,
                              void* d_out, int out_size, void* d_ws, size_t ws_size,
                              hipStream_t stream)
{
  const int*   eidx   = (const int*)d_in[0];
  const float* strf   = (const float*)d_in[1];
  const float* coord  = (const float*)d_in[2];
  const float* msg_w1 = (const float*)d_in[3];
  const float* msg_b1 = (const float*)d_in[4];
  const float* msg_w2 = (const float*)d_in[5];
  const float* msg_b2 = (const float*)d_in[6];
  const float* tr_w1  = (const float*)d_in[7];
  const float* tr_b1  = (const float*)d_in[8];
  const float* tr_w2  = (const float*)d_in[9];
  const float* tr_b2  = (const float*)d_in[10];
  const float* tr_w3  = (const float*)d_in[11];
  const float* posi_w1 = (const float*)d_in[12];
  const float* posi_b1 = (const float*)d_in[13];
  const float* posi_w2 = (const float*)d_in[14];
  const float* posi_b2 = (const float*)d_in[15];
  float* out = (float*)d_out;

  char* ws = (char*)d_ws;
  float* msg_sum   = (float*)ws;                    // [N,256] f32     (zeroed)
  float* trans_sum = msg_sum + NN * 256;            // [N,3]           (zeroed)
  int*   deg       = (int*)(trans_sum + NN * 3);    // [N]             (zeroed)
  int*   cursor    = deg + NN;                      // [N]             (zeroed)
  int*   base      = cursor + NN;                   // [N+8]
  int*   eidg      = base + NN + 8;                 // [E]
  short* strb = (short*)(eidg + NE);                // [N,128] bf16
  short* w1t  = strb + NN * 128;                    // [256][256]
  short* w2t  = w1t + 65536;
  short* t1t  = w2t + 65536;
  short* t2t  = t1t + 65536;
  short* p1t  = t2t + 65536;                        // [256][384]
  short* p2t  = p1t + 98304;                        // [128][256]

  const int* rowp = eidx;

  hipMemsetAsync(ws, 0, (size_t)(NN * 256 + NN * 3 + NN + NN) * 4, stream);
  egcl_prep<<<2048, 256, 0, stream>>>(msg_w1, msg_w2, tr_w1, tr_w2, posi_w1, posi_w2,
                                      strf, rowp, w1t, w2t, t1t, t2t, p1t, p2t, strb, deg);
  egcl_scan<<<1, 1024, 0, stream>>>(deg, base);
  egcl_scatter<<<2560, 256, 0, stream>>>(rowp, base, cursor, eidg);
  egcl_edge<<<NE / 128, 512, 0, stream>>>(eidx, coord, strb, eidg, base, w1t, w2t, t1t, t2t,
                                          msg_w1, msg_b1, msg_b2, tr_b1, tr_b2, tr_w3,
                                          msg_sum, trans_sum);
  egcl_node<<<(NN + 63) / 64, 256, 0, stream>>>(strf, coord, strb, p1t, p2t,
                                                posi_b1, posi_b2,
                                                msg_sum, trans_sum, base, out);
}